// Round 1
// baseline (33515.485 us; speedup 1.0000x reference)
//
#include <hip/hip_runtime.h>
#include <hip/hip_bf16.h>
#include <stdint.h>

// Problem constants (from the reference)
#define T_LEN 2048
#define BATCH 32
#define HID   512
#define GDIM  2048          // 4*HID
#define NL    2
#define NBL   64            // blocks per layer
#define RSL   16            // ring slots (power of 2)
#define UPB   8             // hidden units per block = HID/NBL
#define BH    (BATCH*HID)   // 16384

typedef __attribute__((ext_vector_type(8))) __bf16         bf16x8;
typedef __attribute__((ext_vector_type(8))) unsigned short u16x8;
typedef __attribute__((ext_vector_type(4))) unsigned short u16x4;
typedef __attribute__((ext_vector_type(4))) float          f32x4;

__device__ __forceinline__ unsigned short f2bf(float f) {
  unsigned int u = __builtin_bit_cast(unsigned int, f);
  u += 0x7FFFu + ((u >> 16) & 1u);            // round-to-nearest-even
  return (unsigned short)(u >> 16);
}

__device__ __forceinline__ bf16x8 cvt8(const float* p) {
  const f32x4 a = *(const f32x4*)p;
  const f32x4 b = *(const f32x4*)(p + 4);
  u16x8 r;
  r[0]=f2bf(a[0]); r[1]=f2bf(a[1]); r[2]=f2bf(a[2]); r[3]=f2bf(a[3]);
  r[4]=f2bf(b[0]); r[5]=f2bf(b[1]); r[6]=f2bf(b[2]); r[7]=f2bf(b[3]);
  return __builtin_bit_cast(bf16x8, r);
}

__device__ __forceinline__ float sigm(float x)  { return 1.0f / (1.0f + __expf(-x)); }
__device__ __forceinline__ float tanh_(float x) { return 2.0f / (1.0f + __expf(-2.0f*x)) - 1.0f; }

// Monotonic-flag poll with per-lane cache + deadlock escape hatch.
__device__ __forceinline__ void poll_flag(const int* f, int tgt, int& seen, int* abortp) {
  if (seen >= tgt) return;   // cached from an earlier acquire: already synchronized
  int spins = 0;
  for (;;) {
    int v = __hip_atomic_load(f, __ATOMIC_ACQUIRE, __HIP_MEMORY_SCOPE_AGENT);
    if (v >= tgt) { seen = v; return; }
    if (((++spins) & 255) == 0) {
      if (__hip_atomic_load(abortp, __ATOMIC_RELAXED, __HIP_MEMORY_SCOPE_AGENT) != 0) return;
      if (spins >= (1 << 22)) {  // ~0.5s: protocol broken -> abort whole grid, finish fast
        __hip_atomic_store(abortp, 1, __ATOMIC_RELAXED, __HIP_MEMORY_SCOPE_AGENT);
        return;
      }
    }
  }
}

// ---------------- prep kernels ----------------

__global__ void prep_misc(const float* __restrict__ b_ih, const float* __restrict__ b_hh,
                          const float* __restrict__ h0,
                          int* __restrict__ flags, float* __restrict__ bsum,
                          unsigned short* __restrict__ ring1, unsigned short* __restrict__ ring2) {
  int i = blockIdx.x * blockDim.x + threadIdx.x;           // grid covers 16384
  if (i < 128*16 + 16) flags[i] = 0;                       // flags + abort slot
  if (i < NL*GDIM)     bsum[i] = b_ih[i] + b_hh[i];
  if (i < BH) {
    ring1[i] = f2bf(h0[i]);                                // slot 0 = h0 (layer 0)
    ring2[i] = f2bf(h0[BH + i]);                           // slot 0 = h0 (layer 1)
  }
}

__global__ void prep_w(const float* __restrict__ wih, const float* __restrict__ whh,
                       unsigned short* __restrict__ wihb, unsigned short* __restrict__ whhb) {
  const int n4 = NL*GDIM*HID/4;
  for (int i = blockIdx.x*blockDim.x + threadIdx.x; i < 2*n4; i += gridDim.x*blockDim.x) {
    const float*    src = (i < n4) ? wih  : whh;
    unsigned short* dst = (i < n4) ? wihb : whhb;
    int j = (i < n4) ? i : i - n4;
    f32x4 v = *((const f32x4*)src + j);
    u16x4 o; o[0]=f2bf(v[0]); o[1]=f2bf(v[1]); o[2]=f2bf(v[2]); o[3]=f2bf(v[3]);
    *((u16x4*)dst + j) = o;
  }
}

__global__ void prep_x(const float* __restrict__ x, unsigned short* __restrict__ xbf) {
  const size_t n4 = (size_t)T_LEN*BH/4;
  for (size_t i = blockIdx.x*(size_t)blockDim.x + threadIdx.x; i < n4;
       i += (size_t)gridDim.x*blockDim.x) {
    f32x4 v = *((const f32x4*)x + i);
    u16x4 o; o[0]=f2bf(v[0]); o[1]=f2bf(v[1]); o[2]=f2bf(v[2]); o[3]=f2bf(v[3]);
    *((u16x4*)xbf + i) = o;
  }
}

// ---------------- persistent LSTM kernel ----------------
// 128 blocks x 256 threads. Blocks 0..63 = layer 0, 64..127 = layer 1.
// Block owns UPB hidden units; wave (mh,nh) computes a 16x16 gate tile.
// Flags[b] = number of completed steps of block b (monotonic). Agent-scope
// release on write, acquire on read -> cross-XCD visibility of ring data.

template<bool XBF>
__global__ __launch_bounds__(256, 1) void lstm_persistent(
    const float* __restrict__ x, const unsigned short* __restrict__ xbf,
    const float* __restrict__ c0,
    const unsigned short* __restrict__ wihb, const unsigned short* __restrict__ whhb,
    const float* __restrict__ bsum,
    unsigned short* __restrict__ ring1, unsigned short* __restrict__ ring2,
    int* __restrict__ flags, float* __restrict__ out) {

  const int bid   = blockIdx.x;
  const int layer = bid >> 6;
  const int lb    = bid & 63;
  const int u0    = lb * UPB;
  const int tid   = threadIdx.x;
  const int lane  = tid & 63;
  const int wave  = tid >> 6;
  const int mh  = wave & 1, nh = wave >> 1;
  const int col = lane & 15, kg = lane >> 4;
  const int m   = mh*16 + col;                    // batch row for A-fragments
  const int ul  = nh*4 + (col >> 2);              // unit-local for B-fragment col
  const int gt  = col & 3;                        // gate (i,f,g,o)
  const int grow = gt*HID + u0 + ul;              // global gate row

  // Preload both weight slices as MFMA B-fragments (resident in VGPRs).
  bf16x8 wfx[16], wfh[16];
  {
    const unsigned short* wxr = wihb + ((size_t)layer*GDIM + grow)*HID + kg*8;
    const unsigned short* whr = whhb + ((size_t)layer*GDIM + grow)*HID + kg*8;
#pragma unroll
    for (int ks = 0; ks < 16; ++ks) {
      wfx[ks] = *(const bf16x8*)(wxr + ks*32);
      wfh[ks] = *(const bf16x8*)(whr + ks*32);
    }
  }

  // Elementwise-phase mapping: one thread per (batch, unit).
  const int eb = tid >> 3, eu = tid & 7;
  const int gu = u0 + eu;
  float c = c0[((size_t)layer*BATCH + eb)*HID + gu];
  const float bi  = bsum[layer*GDIM + 0*HID + gu];
  const float bfv = bsum[layer*GDIM + 1*HID + gu];
  const float bg  = bsum[layer*GDIM + 2*HID + gu];
  const float bo  = bsum[layer*GDIM + 3*HID + gu];

  unsigned short* ringW = layer ? ring2 : ring1;
  int* myflag = flags + bid*16;
  int* abortp = flags + 128*16;
  const int* fA = flags + lane*16;            // layer-0 block flags
  const int* fB = flags + (64 + lane)*16;     // layer-1 block flags
  int seenA = 0, seenB = 0;

  __shared__ float sg[32][33];

  for (int t = 0; t < T_LEN; ++t) {
    // ---- dependency wait (all waves poll; cached flags usually skip it) ----
    int tgtA, tgtB;
    if (layer == 0) { tgtA = t;     tgtB = t - (RSL - 2); }  // peers; ring1 backpressure
    else            { tgtA = t + 1; tgtB = t;             }  // producer;   peers
    poll_flag(fA, tgtA, seenA, abortp);
    poll_flag(fB, tgtB, seenB, abortp);

    // ---- gates = x_side @ w_x^T + h_prev @ w_h^T ----
    f32x4 acc = {0.f, 0.f, 0.f, 0.f};
    if (layer == 0) {
      bf16x8 af[16];
      if (XBF) {
        const unsigned short* xr = xbf + (size_t)t*BH + (size_t)m*HID + kg*8;
#pragma unroll
        for (int ks = 0; ks < 16; ++ks) af[ks] = *(const bf16x8*)(xr + ks*32);
      } else {
        const float* xr = x + ((size_t)t*BATCH + m)*HID + kg*8;
#pragma unroll
        for (int ks = 0; ks < 16; ++ks) af[ks] = cvt8(xr + ks*32);
      }
#pragma unroll
      for (int ks = 0; ks < 16; ++ks)
        acc = __builtin_amdgcn_mfma_f32_16x16x32_bf16(af[ks], wfx[ks], acc, 0, 0, 0);
    } else {
      const unsigned short* xr = ring1 + (size_t)((t+1) & (RSL-1))*BH + (size_t)m*HID + kg*8;
      bf16x8 af[16];
#pragma unroll
      for (int ks = 0; ks < 16; ++ks) af[ks] = *(const bf16x8*)(xr + ks*32);
#pragma unroll
      for (int ks = 0; ks < 16; ++ks)
        acc = __builtin_amdgcn_mfma_f32_16x16x32_bf16(af[ks], wfx[ks], acc, 0, 0, 0);
    }
    {
      const unsigned short* hr = ringW + (size_t)(t & (RSL-1))*BH + (size_t)m*HID + kg*8;
      bf16x8 af[16];
#pragma unroll
      for (int ks = 0; ks < 16; ++ks) af[ks] = *(const bf16x8*)(hr + ks*32);
#pragma unroll
      for (int ks = 0; ks < 16; ++ks)
        acc = __builtin_amdgcn_mfma_f32_16x16x32_bf16(af[ks], wfh[ks], acc, 0, 0, 0);
    }

    // ---- gate tile -> LDS (C layout: col=lane&15, row=(lane>>4)*4+j) ----
    {
      const int r  = nh*16 + col;
      const int b0 = mh*16 + kg*4;
      sg[r][b0+0] = acc[0]; sg[r][b0+1] = acc[1];
      sg[r][b0+2] = acc[2]; sg[r][b0+3] = acc[3];
    }
    __syncthreads();

    // ---- LSTM cell update ----
    float gi = sg[eu*4+0][eb] + bi;
    float gf = sg[eu*4+1][eb] + bfv;
    float gg = sg[eu*4+2][eb] + bg;
    float go = sg[eu*4+3][eb] + bo;
    float iv = sigm(gi), fv = sigm(gf), gv = tanh_(gg), ov = sigm(go);
    c = fv*c + iv*gv;
    float h = ov * tanh_(c);

    ringW[(size_t)((t+1) & (RSL-1))*BH + (size_t)eb*HID + gu] = f2bf(h);
    if (layer == 1)
      out[(size_t)t*BH + (size_t)eb*HID + gu] = h;
    if (t == T_LEN - 1) {
      out[(size_t)T_LEN*BH + ((size_t)layer*BATCH + eb)*HID + gu] = h;
      out[(size_t)T_LEN*BH + (size_t)NL*BH + ((size_t)layer*BATCH + eb)*HID + gu] = c;
    }
    __syncthreads();   // drains this block's stores (vmcnt(0) before s_barrier)

    if (tid == 0)
      __hip_atomic_store(myflag, t + 1, __ATOMIC_RELEASE, __HIP_MEMORY_SCOPE_AGENT);
  }
}

// ---------------- host launch ----------------

extern "C" void kernel_launch(void* const* d_in, const int* in_sizes, int n_in,
                              void* d_out, int out_size, void* d_ws, size_t ws_size,
                              hipStream_t stream) {
  const float* x    = (const float*)d_in[0];
  const float* w_ih = (const float*)d_in[1];
  const float* w_hh = (const float*)d_in[2];
  const float* b_ih = (const float*)d_in[3];
  const float* b_hh = (const float*)d_in[4];
  const float* h0   = (const float*)d_in[5];
  const float* c0   = (const float*)d_in[6];
  float* out = (float*)d_out;

  char* ws = (char*)d_ws;
  size_t off = 0;
  auto alloc = [&](size_t bytes) -> void* {
    off = (off + 255) & ~(size_t)255;
    void* p = ws + off;
    off += bytes;
    return p;
  };
  int*            flags = (int*)alloc((128*16 + 16) * sizeof(int));
  float*          bsum  = (float*)alloc((size_t)NL*GDIM*sizeof(float));
  unsigned short* ring1 = (unsigned short*)alloc((size_t)RSL*BH*2);
  unsigned short* ring2 = (unsigned short*)alloc((size_t)RSL*BH*2);
  unsigned short* wihb  = (unsigned short*)alloc((size_t)NL*GDIM*HID*2);
  unsigned short* whhb  = (unsigned short*)alloc((size_t)NL*GDIM*HID*2);

  // Optional bf16 copy of x (halves per-step broadcast traffic) if ws allows.
  unsigned short* xbf = nullptr;
  {
    size_t noff = (off + 255) & ~(size_t)255;
    size_t xbytes = (size_t)T_LEN*BH*2;
    if (noff + xbytes <= ws_size) xbf = (unsigned short*)(ws + noff);
  }

  prep_misc<<<64, 256, 0, stream>>>(b_ih, b_hh, h0, flags, bsum, ring1, ring2);
  prep_w<<<1024, 256, 0, stream>>>(w_ih, w_hh, wihb, whhb);
  if (xbf) {
    prep_x<<<2048, 256, 0, stream>>>(x, xbf);
    lstm_persistent<true><<<128, 256, 0, stream>>>(x, xbf, c0, wihb, whhb, bsum,
                                                   ring1, ring2, flags, out);
  } else {
    lstm_persistent<false><<<128, 256, 0, stream>>>(x, xbf, c0, wihb, whhb, bsum,
                                                    ring1, ring2, flags, out);
  }
  (void)in_sizes; (void)n_in; (void)out_size;
}

// Round 2
// 11687.504 us; speedup vs baseline: 2.8676x; 2.8676x over previous
//
#include <hip/hip_runtime.h>
#include <hip/hip_bf16.h>
#include <stdint.h>

// Problem constants (from the reference)
#define T_LEN 2048
#define BATCH 32
#define HID   512
#define GDIM  2048          // 4*HID
#define NL    2
#define NBL   64            // blocks per layer
#define RSL   16            // ring slots (power of 2)
#define UPB   8             // hidden units per block = HID/NBL
#define BH    (BATCH*HID)   // 16384

typedef __attribute__((ext_vector_type(8))) __bf16         bf16x8;
typedef __attribute__((ext_vector_type(8))) unsigned short u16x8;
typedef __attribute__((ext_vector_type(4))) unsigned short u16x4;
typedef __attribute__((ext_vector_type(4))) float          f32x4;

__device__ __forceinline__ unsigned short f2bf(float f) {
  unsigned int u = __builtin_bit_cast(unsigned int, f);
  u += 0x7FFFu + ((u >> 16) & 1u);            // round-to-nearest-even
  return (unsigned short)(u >> 16);
}

__device__ __forceinline__ bf16x8 cvt8(const float* p) {
  const f32x4 a = *(const f32x4*)p;
  const f32x4 b = *(const f32x4*)(p + 4);
  u16x8 r;
  r[0]=f2bf(a[0]); r[1]=f2bf(a[1]); r[2]=f2bf(a[2]); r[3]=f2bf(a[3]);
  r[4]=f2bf(b[0]); r[5]=f2bf(b[1]); r[6]=f2bf(b[2]); r[7]=f2bf(b[3]);
  return __builtin_bit_cast(bf16x8, r);
}

__device__ __forceinline__ float sigm(float x)  { return 1.0f / (1.0f + __expf(-x)); }
__device__ __forceinline__ float tanh_(float x) { return 2.0f / (1.0f + __expf(-2.0f*x)) - 1.0f; }

// L2-bypassing (agent-coherent, sc1) 16B load/2B store: data moves via L3,
// so NO buffer_inv / buffer_wbl2 cache maintenance is ever required.
__device__ __forceinline__ bf16x8 ld16_sc1(const void* p) {
  f32x4 r;
  asm volatile("global_load_dwordx4 %0, %1, off sc1" : "=v"(r) : "v"(p));
  return __builtin_bit_cast(bf16x8, r);
}
__device__ __forceinline__ void st2_sc1(void* p, unsigned short v) {
  unsigned int vv = v;
  asm volatile("global_store_short %0, %1, off sc1" :: "v"(p), "v"(vv) : "memory");
}

// Relaxed-only spin (each iteration = one plain sc1 dword load; no waitcnt,
// no cache invalidation). Per-lane flag caching + deadlock escape hatch.
__device__ __forceinline__ void poll2(const int* fa, int ta, int& seenA,
                                      const int* fb, int tb, int& seenB,
                                      int* abortp) {
  if (seenA >= ta && seenB >= tb) return;
  int spins = 0;
  for (;;) {
    if (seenA < ta) {
      int v = __hip_atomic_load(fa, __ATOMIC_RELAXED, __HIP_MEMORY_SCOPE_AGENT);
      if (v > seenA) seenA = v;
    }
    if (seenB < tb) {
      int v = __hip_atomic_load(fb, __ATOMIC_RELAXED, __HIP_MEMORY_SCOPE_AGENT);
      if (v > seenB) seenB = v;
    }
    if (seenA >= ta && seenB >= tb) return;
    if (((++spins) & 255) == 0) {
      if (__hip_atomic_load(abortp, __ATOMIC_RELAXED, __HIP_MEMORY_SCOPE_AGENT) != 0) return;
      if (spins >= (1 << 22)) {   // ~1s: protocol broken -> abort grid, finish fast
        __hip_atomic_store(abortp, 1, __ATOMIC_RELAXED, __HIP_MEMORY_SCOPE_AGENT);
        return;
      }
    }
  }
}

// ---------------- prep kernels ----------------

__global__ void prep_misc(const float* __restrict__ b_ih, const float* __restrict__ b_hh,
                          const float* __restrict__ h0,
                          int* __restrict__ flags, float* __restrict__ bsum,
                          unsigned short* __restrict__ ring1, unsigned short* __restrict__ ring2) {
  int i = blockIdx.x * blockDim.x + threadIdx.x;           // grid covers 16384
  if (i < 128*16 + 16) flags[i] = 0;                       // flags + abort slot
  if (i < NL*GDIM)     bsum[i] = b_ih[i] + b_hh[i];
  if (i < BH) {
    ring1[i] = f2bf(h0[i]);                                // slot 0 = h0 (layer 0)
    ring2[i] = f2bf(h0[BH + i]);                           // slot 0 = h0 (layer 1)
  }
}

__global__ void prep_w(const float* __restrict__ wih, const float* __restrict__ whh,
                       unsigned short* __restrict__ wihb, unsigned short* __restrict__ whhb) {
  const int n4 = NL*GDIM*HID/4;
  for (int i = blockIdx.x*blockDim.x + threadIdx.x; i < 2*n4; i += gridDim.x*blockDim.x) {
    const float*    src = (i < n4) ? wih  : whh;
    unsigned short* dst = (i < n4) ? wihb : whhb;
    int j = (i < n4) ? i : i - n4;
    f32x4 v = *((const f32x4*)src + j);
    u16x4 o; o[0]=f2bf(v[0]); o[1]=f2bf(v[1]); o[2]=f2bf(v[2]); o[3]=f2bf(v[3]);
    *((u16x4*)dst + j) = o;
  }
}

__global__ void prep_x(const float* __restrict__ x, unsigned short* __restrict__ xbf) {
  const size_t n4 = (size_t)T_LEN*BH/4;
  for (size_t i = blockIdx.x*(size_t)blockDim.x + threadIdx.x; i < n4;
       i += (size_t)gridDim.x*blockDim.x) {
    f32x4 v = *((const f32x4*)x + i);
    u16x4 o; o[0]=f2bf(v[0]); o[1]=f2bf(v[1]); o[2]=f2bf(v[2]); o[3]=f2bf(v[3]);
    *((u16x4*)xbf + i) = o;
  }
}

// ---------------- persistent LSTM kernel ----------------
// 128 blocks x 256 threads. Blocks 0..63 = layer 0, 64..127 = layer 1.
// All cross-block data (rings) moves via sc1 (L2-bypass, coherent at L3).
// Flags: relaxed agent atomics (sc1 dword). Publish order is guaranteed by
// explicit `s_waitcnt vmcnt(0)` before the flag store; consume order by
// in-order issue after the poll's compare-branch.

template<bool XBF>
__global__ __launch_bounds__(256, 1) void lstm_persistent(
    const float* __restrict__ x, const unsigned short* __restrict__ xbf,
    const float* __restrict__ c0,
    const unsigned short* __restrict__ wihb, const unsigned short* __restrict__ whhb,
    const float* __restrict__ bsum,
    unsigned short* __restrict__ ring1, unsigned short* __restrict__ ring2,
    int* __restrict__ flags, float* __restrict__ out) {

  const int bid   = blockIdx.x;
  const int layer = bid >> 6;
  const int tid   = threadIdx.x;
  const int lane  = tid & 63;
  const int wave  = tid >> 6;
  const int mh  = wave & 1, nh = wave >> 1;
  const int col = lane & 15, kg = lane >> 4;
  const int m   = mh*16 + col;                    // batch row for A-fragments
  const int u0  = (bid & 63) * UPB;
  const int ul  = nh*4 + (col >> 2);              // unit-local for B-fragment col
  const int gt  = col & 3;                        // gate (i,f,g,o)
  const int grow = gt*HID + u0 + ul;              // global gate row

  // Preload both weight slices as MFMA B-fragments (resident in reg file).
  bf16x8 wfx[16], wfh[16];
  {
    const unsigned short* wxr = wihb + ((size_t)layer*GDIM + grow)*HID + kg*8;
    const unsigned short* whr = whhb + ((size_t)layer*GDIM + grow)*HID + kg*8;
#pragma unroll
    for (int ks = 0; ks < 16; ++ks) {
      wfx[ks] = *(const bf16x8*)(wxr + ks*32);
      wfh[ks] = *(const bf16x8*)(whr + ks*32);
    }
  }

  // Elementwise-phase mapping: one thread per (batch, unit).
  const int eb = tid >> 3, eu = tid & 7;
  const int gu = u0 + eu;
  float c = c0[((size_t)layer*BATCH + eb)*HID + gu];
  const float bi  = bsum[layer*GDIM + 0*HID + gu];
  const float bfv = bsum[layer*GDIM + 1*HID + gu];
  const float bg  = bsum[layer*GDIM + 2*HID + gu];
  const float bo  = bsum[layer*GDIM + 3*HID + gu];

  unsigned short* ringW = layer ? ring2 : ring1;
  int* myflag = flags + bid*16;
  int* abortp = flags + 128*16;
  const int* fA = flags + lane*16;            // layer-0 block flags
  const int* fB = flags + (64 + lane)*16;     // layer-1 block flags
  int seenA = 0, seenB = 0;

  __shared__ float sg[32][33];

  for (int t = 0; t < T_LEN; ++t) {
    // ---- dependency wait (relaxed polls only) ----
    if (layer == 0) poll2(fA, t,     seenA, fB, t - (RSL - 2), seenB, abortp);
    else            poll2(fA, t + 1, seenA, fB, t,             seenB, abortp);
    asm volatile("" ::: "memory");

    // ---- fragment loads: h-side (sc1) first, then x-side ----
    bf16x8 ah[16], ax[16];
    {
      const unsigned short* hr = ringW + (size_t)(t & (RSL-1))*BH + (size_t)m*HID + kg*8;
#pragma unroll
      for (int ks = 0; ks < 16; ++ks) ah[ks] = ld16_sc1(hr + ks*32);
    }
    if (layer == 0) {
      if (XBF) {
        const unsigned short* xr = xbf + (size_t)t*BH + (size_t)m*HID + kg*8;
#pragma unroll
        for (int ks = 0; ks < 16; ++ks) ax[ks] = *(const bf16x8*)(xr + ks*32);
      } else {
        const float* xr = x + ((size_t)t*BATCH + m)*HID + kg*8;
#pragma unroll
        for (int ks = 0; ks < 16; ++ks) ax[ks] = cvt8(xr + ks*32);
      }
    } else {
      const unsigned short* xr = ring1 + (size_t)((t+1) & (RSL-1))*BH + (size_t)m*HID + kg*8;
#pragma unroll
      for (int ks = 0; ks < 16; ++ks) ax[ks] = ld16_sc1(xr + ks*32);
    }
    asm volatile("s_waitcnt vmcnt(0)" ::: "memory");
    __builtin_amdgcn_sched_barrier(0);

    // ---- two independent MFMA chains (compiler interleaves) ----
    f32x4 accx = {0.f,0.f,0.f,0.f}, acch = {0.f,0.f,0.f,0.f};
#pragma unroll
    for (int ks = 0; ks < 16; ++ks) {
      accx = __builtin_amdgcn_mfma_f32_16x16x32_bf16(ax[ks], wfx[ks], accx, 0, 0, 0);
      acch = __builtin_amdgcn_mfma_f32_16x16x32_bf16(ah[ks], wfh[ks], acch, 0, 0, 0);
    }
    const f32x4 acc = accx + acch;

    // ---- gate tile -> LDS (C layout: col=lane&15, row=(lane>>4)*4+j) ----
    {
      const int r  = nh*16 + col;
      const int b0 = mh*16 + kg*4;
      sg[r][b0+0] = acc[0]; sg[r][b0+1] = acc[1];
      sg[r][b0+2] = acc[2]; sg[r][b0+3] = acc[3];
    }
    __syncthreads();

    // ---- LSTM cell update ----
    float gi = sg[eu*4+0][eb] + bi;
    float gf = sg[eu*4+1][eb] + bfv;
    float gg = sg[eu*4+2][eb] + bg;
    float go = sg[eu*4+3][eb] + bo;
    float iv = sigm(gi), fv = sigm(gf), gv = tanh_(gg), ov = sigm(go);
    c = fv*c + iv*gv;
    float h = ov * tanh_(c);

    st2_sc1(ringW + (size_t)((t+1) & (RSL-1))*BH + (size_t)eb*HID + gu, f2bf(h));
    if (layer == 1)
      out[(size_t)t*BH + (size_t)eb*HID + gu] = h;
    if (t == T_LEN - 1) {
      out[(size_t)T_LEN*BH + ((size_t)layer*BATCH + eb)*HID + gu] = h;
      out[(size_t)T_LEN*BH + (size_t)NL*BH + ((size_t)layer*BATCH + eb)*HID + gu] = c;
    }

    // Drain this wave's sc1 stores to the coherence point, then block-wide
    // barrier, then publish. (Explicit drain: the compiler can't count our
    // inline-asm stores in its pre-barrier waitcnt.)
    asm volatile("s_waitcnt vmcnt(0)" ::: "memory");
    __syncthreads();
    if (tid == 0)
      __hip_atomic_store(myflag, t + 1, __ATOMIC_RELAXED, __HIP_MEMORY_SCOPE_AGENT);
  }
}

// ---------------- host launch ----------------

extern "C" void kernel_launch(void* const* d_in, const int* in_sizes, int n_in,
                              void* d_out, int out_size, void* d_ws, size_t ws_size,
                              hipStream_t stream) {
  const float* x    = (const float*)d_in[0];
  const float* w_ih = (const float*)d_in[1];
  const float* w_hh = (const float*)d_in[2];
  const float* b_ih = (const float*)d_in[3];
  const float* b_hh = (const float*)d_in[4];
  const float* h0   = (const float*)d_in[5];
  const float* c0   = (const float*)d_in[6];
  float* out = (float*)d_out;

  char* ws = (char*)d_ws;
  size_t off = 0;
  auto alloc = [&](size_t bytes) -> void* {
    off = (off + 255) & ~(size_t)255;
    void* p = ws + off;
    off += bytes;
    return p;
  };
  int*            flags = (int*)alloc((128*16 + 16) * sizeof(int));
  float*          bsum  = (float*)alloc((size_t)NL*GDIM*sizeof(float));
  unsigned short* ring1 = (unsigned short*)alloc((size_t)RSL*BH*2);
  unsigned short* ring2 = (unsigned short*)alloc((size_t)RSL*BH*2);
  unsigned short* wihb  = (unsigned short*)alloc((size_t)NL*GDIM*HID*2);
  unsigned short* whhb  = (unsigned short*)alloc((size_t)NL*GDIM*HID*2);

  // Optional bf16 copy of x (halves per-step broadcast traffic) if ws allows.
  unsigned short* xbf = nullptr;
  {
    size_t noff = (off + 255) & ~(size_t)255;
    size_t xbytes = (size_t)T_LEN*BH*2;
    if (noff + xbytes <= ws_size) xbf = (unsigned short*)(ws + noff);
  }

  prep_misc<<<64, 256, 0, stream>>>(b_ih, b_hh, h0, flags, bsum, ring1, ring2);
  prep_w<<<1024, 256, 0, stream>>>(w_ih, w_hh, wihb, whhb);
  if (xbf) {
    prep_x<<<2048, 256, 0, stream>>>(x, xbf);
    lstm_persistent<true><<<128, 256, 0, stream>>>(x, xbf, c0, wihb, whhb, bsum,
                                                   ring1, ring2, flags, out);
  } else {
    lstm_persistent<false><<<128, 256, 0, stream>>>(x, xbf, c0, wihb, whhb, bsum,
                                                    ring1, ring2, flags, out);
  }
  (void)in_sizes; (void)n_in; (void)out_size;
}

// Round 6
// 8962.176 us; speedup vs baseline: 3.7397x; 1.3041x over previous
//
#include <hip/hip_runtime.h>
#include <hip/hip_bf16.h>
#include <stdint.h>

// Problem constants
#define T_LEN 2048
#define BATCH 32
#define HID   512
#define GDIM  2048            // 4*HID
#define NL    2
#define NBL   32              // blocks per layer
#define UPB   16              // hidden units per block
#define RSL   16              // ring slots
#define BH    (BATCH*HID)     // 16384
#define SLOTB (BH*2)          // 32768 B per ring slot (bf16, fragment-major)
#define RINGB (RSL*SLOTB)     // 512 KB per ring

// flag zone (ints): flagsA[64*32] | flagsB[64*32] | detect[64] | abort
#define FZ_FB   2048
#define FZ_DET  4096
#define FZ_ABT  4160
#define FZ_TOT  4224

typedef __attribute__((ext_vector_type(8))) __bf16         bf16x8;
typedef __attribute__((ext_vector_type(8))) unsigned short u16x8;
typedef __attribute__((ext_vector_type(4))) unsigned short u16x4;
typedef __attribute__((ext_vector_type(4))) float          f32x4;

__device__ __forceinline__ unsigned short f2bf(float f) {
  unsigned int u = __builtin_bit_cast(unsigned int, f);
  u += 0x7FFFu + ((u >> 16) & 1u);
  return (unsigned short)(u >> 16);
}
__device__ __forceinline__ f32x4 pack8(f32x4 a, f32x4 b) {   // 8 f32 -> bf16x8 bits
  u16x8 r;
  r[0]=f2bf(a[0]); r[1]=f2bf(a[1]); r[2]=f2bf(a[2]); r[3]=f2bf(a[3]);
  r[4]=f2bf(b[0]); r[5]=f2bf(b[1]); r[6]=f2bf(b[2]); r[7]=f2bf(b[3]);
  return __builtin_bit_cast(f32x4, r);
}
__device__ __forceinline__ float sigm(float x)  { return 1.0f / (1.0f + __expf(-x)); }
__device__ __forceinline__ float tanh_(float x) { return 2.0f / (1.0f + __expf(-2.0f*x)) - 1.0f; }

// ---- scoped memory helpers. Loads embed their own waitcnt (the compiler
// cannot track inline-asm loads) unless the caller drains explicitly. ----
__device__ __forceinline__ f32x4 ld16_pl(const void* p)  { f32x4 r; asm volatile("global_load_dwordx4 %0, %1, off"     : "=v"(r) : "v"(p)); return r; }
__device__ __forceinline__ f32x4 ld16_sc0(const void* p) { f32x4 r; asm volatile("global_load_dwordx4 %0, %1, off sc0" : "=v"(r) : "v"(p)); return r; }
__device__ __forceinline__ f32x4 ld16_sc1(const void* p) { f32x4 r; asm volatile("global_load_dwordx4 %0, %1, off sc1" : "=v"(r) : "v"(p)); return r; }
__device__ __forceinline__ int lddww_sc1(const void* p) {
  int r; asm volatile("global_load_dword %0, %1, off sc1\n\ts_waitcnt vmcnt(0)" : "=v"(r) : "v"(p) : "memory"); return r;
}
__device__ __forceinline__ void st2_sc0(void* p, unsigned short v) {
  unsigned int vv = v; asm volatile("global_store_short %0, %1, off sc0" :: "v"(p), "v"(vv) : "memory");
}
__device__ __forceinline__ void st2_sc1(void* p, unsigned short v) {
  unsigned int vv = v; asm volatile("global_store_short %0, %1, off sc1" :: "v"(p), "v"(vv) : "memory");
}
__device__ __forceinline__ void stdw_sc1(void* p, int v) { asm volatile("global_store_dword %0, %1, off sc1" :: "v"(p), "v"(v) : "memory"); }
__device__ __forceinline__ void vm_drain() { asm volatile("s_waitcnt vmcnt(0)" ::: "memory"); }

// ---------------- prep kernels ----------------

__global__ void prep_misc(const float* __restrict__ b_ih, const float* __restrict__ b_hh,
                          const float* __restrict__ h0,
                          int* __restrict__ flagz, float* __restrict__ bsum,
                          char* __restrict__ ring0, char* __restrict__ ring1s) {
  int i = blockIdx.x * blockDim.x + threadIdx.x;   // 16384 threads
  if (i < FZ_TOT) flagz[i] = 0;
  if (i < NL*GDIM) bsum[i] = b_ih[i] + b_hh[i];
  if (i < NL*2048) {                                // ring slot-0 init, fragment-major
    int layer = i >> 11, id = i & 2047;
    int mh = id >> 10, ks = (id >> 6) & 15, lf = id & 63;
    int c2 = lf & 15, k2 = lf >> 4;
    const float* s = h0 + ((size_t)(layer*BATCH + mh*16 + c2))*HID + ks*32 + k2*8;
    f32x4 v = pack8(*(const f32x4*)s, *(const f32x4*)(s+4));
    *(f32x4*)(ring0  + (size_t)layer*RINGB + (size_t)id*16) = v;
    *(f32x4*)(ring1s + (size_t)layer*RINGB + (size_t)id*16) = v;
  }
}

__global__ void prep_w(const float* __restrict__ wih, const float* __restrict__ whh,
                       unsigned short* __restrict__ wihb, unsigned short* __restrict__ whhb) {
  const int n4 = NL*GDIM*HID/4;
  for (int i = blockIdx.x*blockDim.x + threadIdx.x; i < 2*n4; i += gridDim.x*blockDim.x) {
    const float*    src = (i < n4) ? wih  : whh;
    unsigned short* dst = (i < n4) ? wihb : whhb;
    int j = (i < n4) ? i : i - n4;
    f32x4 v = *((const f32x4*)src + j);
    u16x4 o; o[0]=f2bf(v[0]); o[1]=f2bf(v[1]); o[2]=f2bf(v[2]); o[3]=f2bf(v[3]);
    *((u16x4*)dst + j) = o;
  }
}

// ---------------- persistent LSTM ----------------
// grid 256 x 512. Active: bid%8 < 2 (layer), lb = bid>>3 in [0,32). 32 blocks/layer.
// REPLAY-SAFETY RULE (round-5 lesson): L2 retains stale lines across kernel
// launches, so sc0 (L2-scope) accesses are allowed ONLY for value-guarded ring
// DATA whose producer (same XCD) rewrites the line this launch before the flag
// says "ready". All control state (flags/detect/abort) is sc1-only: sc1 loads
// read L3 directly (no stale-L2 hazard) and sc1 stores are write-through (no
// dirty flag lines that could write back late into the next replay).
// t=0 h reads are flag-unguarded -> forced to the sc1 ring (prep-written).
//
// flagsA (own-layer, eager): A == t+1  =>  h(t) visible in the mode's ring.
// flagsB (cross-layer): layer-0-fast publishes lagged (B == t at end of iter t
//   => ringS mirror h(t-1) drained + visible); others eager (B == t+1).
// Layer-1 iter t waits layer-0 B >= t+1; layer-0 iter t waits layer-1 B >= t-14.
// Terminal publish (round-4 fix): after the loop, A = B = T_LEN+1.
// No thread ever breaks out of the t-loop: aborts only disable polling, so all
// waves execute an identical barrier sequence (hang-proof).

__global__ __launch_bounds__(512) void lstm_persist(
    const float* __restrict__ x, const float* __restrict__ c0,
    const unsigned short* __restrict__ wihb, const unsigned short* __restrict__ whhb,
    const float* __restrict__ bsum,
    char* __restrict__ ring0, char* __restrict__ ring1s,
    int* __restrict__ flagz, float* __restrict__ out) {

  const int bid = blockIdx.x;
  const int r8  = bid & 7;
  if (r8 >= NL) return;
  const int layer = r8;
  const int lb    = bid >> 3;                 // 0..31
  const int actIdx = layer*NBL + lb;          // 0..63
  const int tid  = threadIdx.x;
  const int lane = tid & 63;
  const int wave = tid >> 6;                  // 0..7
  const int mh = wave & 1, nh = wave >> 1;    // batch-half, row-group (0..3)
  const int col = lane & 15, kg = lane >> 4;
  const int gt  = col & 3;                    // gate index (i,f,g,o)
  const int uu  = nh*4 + (col >> 2);          // unit-local 0..15
  const int u0  = lb * UPB;
  const int gu  = u0 + uu;                    // global hidden unit
  const int grow = gt*HID + gu;               // gate-matrix row
  const int tb  = mh*16 + kg*4 + gt;          // this thread's batch (post-transpose)

  int* flagsA = flagz;
  int* flagsB = flagz + FZ_FB;
  int* detect = flagz + FZ_DET;
  int* abortp = flagz + FZ_ABT;

  __shared__ __align__(16) f32x4 smem[4096];  // h frags [0,2048), x frags [2048,4096)

  // ---- weight fragments pinned in VGPRs (opaque touch defeats remat) ----
  f32x4 wfx[16], wfh[16];
  {
    const unsigned short* wxr = wihb + ((size_t)(layer*GDIM + grow))*HID + kg*8;
    const unsigned short* whr = whhb + ((size_t)(layer*GDIM + grow))*HID + kg*8;
#pragma unroll
    for (int ks = 0; ks < 16; ++ks) {
      f32x4 a = *(const f32x4*)(wxr + ks*32);
      f32x4 b = *(const f32x4*)(whr + ks*32);
      asm volatile("" : "+v"(a));
      asm volatile("" : "+v"(b));
      wfx[ks] = a; wfh[ks] = b;
    }
  }

  // ---- per-thread cell state ----
  float c = c0[((size_t)layer*BATCH + tb)*HID + gu];
  const float bi  = bsum[layer*GDIM + 0*HID + gu];
  const float bfv = bsum[layer*GDIM + 1*HID + gu];
  const float bg  = bsum[layer*GDIM + 2*HID + gu];
  const float bo  = bsum[layer*GDIM + 3*HID + gu];

  // ring byte offset for this thread's h element (fragment-major layout)
  const int se = ((tb>>4)*8192 + (gu>>5)*512 + (tb&15)*8 + ((gu>>3)&3)*128 + (gu&7)) * 2;

  char* ringF = ring0  + (size_t)layer*RINGB;   // sc0 own-layer ring (fast data)
  char* ringS = ring1s + (size_t)layer*RINGB;   // sc1 own-layer ring
  const char* ringPrev = ring1s;                 // layer-0's sc1 ring (x for layer 1)
  int* myfA = flagsA + actIdx*32;
  int* myfB = flagsB + actIdx*32;
  const bool pl = lane < NBL;
  const int* fpOwnA = flagsA + (layer*NBL + lane)*32;
  const int* fpOthB = flagsB + ((1-layer)*NBL + lane)*32;
  int seenOwn = 0, seenOth = 0;
  bool dead = false;

  // ---- placement detection (all blocks report, all blocks vote; sc1-only) ----
  int xcc = 0;
  asm volatile("s_getreg_b32 %0, hwreg(HW_REG_XCC_ID)" : "=s"(xcc));
  if (tid == 0) stdw_sc1(detect + actIdx, xcc + 1);
  int dv = 0;
  {
    int spins = 0;
    for (;;) {
      if (dv == 0) dv = lddww_sc1(detect + lane);
      if (__all(dv != 0)) break;
      if (((++spins) & 255) == 0) {
        if (lddww_sc1(abortp)) { dead = true; break; }
        if (spins >= (1 << 20)) { stdw_sc1(abortp, 1); dead = true; break; }
      }
    }
  }
  const int dref0 = __shfl(dv, 0, 64), dref1 = __shfl(dv, 32, 64);
  const bool fastL0 = __all((lane < 32) ? (dv != 0 && dv == dref0) : 1);
  const bool fastL1 = __all((lane >= 32) ? (dv != 0 && dv == dref1) : 1);
  const bool fast = (layer ? fastL1 : fastL0) && !dead;

  for (int t = 0; t < T_LEN; ++t) {
    const int slotR = t & (RSL-1);
    const int slotW = (t+1) & (RSL-1);

    // ---- 1. x prefetch (layer 0: plain f32 loads, no dependencies) ----
    f32x4 xpre[8];
    if (layer == 0) {
#pragma unroll
      for (int q = 0; q < 4; ++q) {
        int id = q*512 + tid;
        int mh2 = id >> 10, ks2 = (id >> 6) & 15, lf = id & 63;
        int c2 = lf & 15, k2 = lf >> 4;
        const float* s = x + ((size_t)t*BATCH + mh2*16 + c2)*HID + ks2*32 + k2*8;
        xpre[2*q]   = ld16_pl(s);
        xpre[2*q+1] = ld16_pl(s + 4);
      }
    }

    // ---- 2. phase A: other-layer flagsB (sc1) ----
    if (!dead) {
      const int tgt = (layer == 0) ? (t - 14) : (t + 1);
      int spins = 0;
      while (!__all(pl ? (seenOth >= tgt) : 1)) {
        if (pl && seenOth < tgt) { int v = lddww_sc1(fpOthB); if (v > seenOth) seenOth = v; }
        if (((++spins) & 255) == 0) {
          if (lddww_sc1(abortp)) { dead = true; break; }
          if (spins >= (1 << 21)) { stdw_sc1(abortp, 1); dead = true; break; }
        }
      }
    }

    // ---- 3. layer-1: x-side loads from layer-0's sc1 ring ----
    f32x4 xq[4];
    if (layer == 1) {
      const char* p = ringPrev + (size_t)slotW*SLOTB;
#pragma unroll
      for (int q = 0; q < 4; ++q) xq[q] = ld16_sc1(p + (size_t)(q*512 + tid)*16);
    }

    // ---- 4. phase B: own-layer flagsA (sc1) ----
    if (!dead) {
      int spins = 0;
      while (!__all(pl ? (seenOwn >= t) : 1)) {
        if (pl && seenOwn < t) { int v = lddww_sc1(fpOwnA); if (v > seenOwn) seenOwn = v; }
        if (((++spins) & 255) == 0) {
          if (lddww_sc1(abortp)) { dead = true; break; }
          if (spins >= (1 << 21)) { stdw_sc1(abortp, 1); dead = true; break; }
        }
      }
    }

    // ---- 5. h loads. Fast path reads the sc0 ring EXCEPT t==0 (flag-unguarded
    // initial data -> sc1 ring written by prep; stale-L2-safe). ----
    f32x4 hq[4];
    if (fast && t > 0) {
      const char* p = ringF + (size_t)slotR*SLOTB;
#pragma unroll
      for (int q = 0; q < 4; ++q) hq[q] = ld16_sc0(p + (size_t)(q*512 + tid)*16);
    } else {
      const char* p = ringS + (size_t)slotR*SLOTB;
#pragma unroll
      for (int q = 0; q < 4; ++q) hq[q] = ld16_sc1(p + (size_t)(q*512 + tid)*16);
    }
    vm_drain();   // all asm loads (xpre/xq/hq) valid; deferred stores from t-1 drained

    // ---- 6. stage to LDS (linear, fragment-major) ----
#pragma unroll
    for (int q = 0; q < 4; ++q) smem[q*512 + tid] = hq[q];
    if (layer == 0) {
#pragma unroll
      for (int q = 0; q < 4; ++q) smem[2048 + q*512 + tid] = pack8(xpre[2*q], xpre[2*q+1]);
    } else {
#pragma unroll
      for (int q = 0; q < 4; ++q) smem[2048 + q*512 + tid] = xq[q];
    }
    __syncthreads();   // B1

    // ---- 7. fragment reads + two independent MFMA chains ----
    f32x4 accx = {0.f,0.f,0.f,0.f}, acch = {0.f,0.f,0.f,0.f};
    {
      const f32x4* hb = (const f32x4*)smem;
      const f32x4* xb = (const f32x4*)smem + 2048;
#pragma unroll
      for (int ks = 0; ks < 16; ++ks) {
        f32x4 ah = hb[(mh*16 + ks)*64 + lane];
        f32x4 av = xb[(mh*16 + ks)*64 + lane];
        accx = __builtin_amdgcn_mfma_f32_16x16x32_bf16(
                 __builtin_bit_cast(bf16x8, av), __builtin_bit_cast(bf16x8, wfx[ks]), accx, 0,0,0);
        acch = __builtin_amdgcn_mfma_f32_16x16x32_bf16(
                 __builtin_bit_cast(bf16x8, ah), __builtin_bit_cast(bf16x8, wfh[ks]), acch, 0,0,0);
      }
    }
    const f32x4 acc = accx + acch;

    // ---- 8. in-wave 4x4 butterfly transpose: (4 batches x 1 gate) -> (1 batch x 4 gates)
    float m0 = acc[0], m1 = acc[1], m2 = acc[2], m3 = acc[3];
    {
      float s0 = __shfl_xor(m0, 1), s1 = __shfl_xor(m1, 1),
            s2 = __shfl_xor(m2, 1), s3 = __shfl_xor(m3, 1);
      if (gt & 1) { m0 = s1; m2 = s3; } else { m1 = s0; m3 = s2; }
      s0 = __shfl_xor(m0, 2); s1 = __shfl_xor(m1, 2);
      s2 = __shfl_xor(m2, 2); s3 = __shfl_xor(m3, 2);
      if (gt & 2) { m0 = s2; m1 = s3; } else { m2 = s0; m3 = s1; }
    }
    // m0..m3 = gates i,f,g,o for (batch tb, unit gu)
    const float iv = sigm(m0 + bi), fv = sigm(m1 + bfv);
    const float gv = tanh_(m2 + bg), ov = sigm(m3 + bo);
    c = fv*c + iv*gv;
    const float h = ov * tanh_(c);
    const unsigned short hsh = f2bf(h);

    // ---- 9. publish h (critical ring first), drain, barrier, flags (sc1) ----
    if (fast) st2_sc0(ringF + (size_t)slotW*SLOTB + se, hsh);
    else      st2_sc1(ringS + (size_t)slotW*SLOTB + se, hsh);
    vm_drain();
    __syncthreads();   // B4: all waves' stores are at their coherence point
    if (tid == 0)  stdw_sc1(myfA, t + 1);
    if (tid == 64) stdw_sc1(myfB, (layer == 0 && fast) ? t : (t + 1));

    // ---- 10. deferred sc1 mirror (layer-0 fast; drained by next iter's drain) ----
    if (layer == 0 && fast) st2_sc1(ringS + (size_t)slotW*SLOTB + se, hsh);
    if (layer == 1) out[(size_t)t*BH + (size_t)tb*HID + gu] = h;
    if (t == T_LEN-1) {
      out[(size_t)T_LEN*BH + ((size_t)layer*BATCH + tb)*HID + gu] = h;
      out[(size_t)T_LEN*BH + (size_t)NL*BH + ((size_t)layer*BATCH + tb)*HID + gu] = c;
    }
  }

  // ---- terminal publish: drain ALL deferred stores, then advertise completion
  // past any possible wait target (max target is T_LEN for layer-1's phase A).
  vm_drain();
  __syncthreads();
  if (tid == 0)  stdw_sc1(myfA, T_LEN + 1);
  if (tid == 64) stdw_sc1(myfB, T_LEN + 1);
}

// ---------------- host launch ----------------

extern "C" void kernel_launch(void* const* d_in, const int* in_sizes, int n_in,
                              void* d_out, int out_size, void* d_ws, size_t ws_size,
                              hipStream_t stream) {
  const float* x    = (const float*)d_in[0];
  const float* w_ih = (const float*)d_in[1];
  const float* w_hh = (const float*)d_in[2];
  const float* b_ih = (const float*)d_in[3];
  const float* b_hh = (const float*)d_in[4];
  const float* h0   = (const float*)d_in[5];
  const float* c0   = (const float*)d_in[6];
  float* out = (float*)d_out;

  char* ws = (char*)d_ws;
  size_t off = 0;
  auto alloc = [&](size_t bytes) -> void* {
    off = (off + 255) & ~(size_t)255;
    void* p = ws + off;
    off += bytes;
    return p;
  };
  int*            flagz = (int*)alloc((size_t)FZ_TOT * sizeof(int));
  float*          bsum  = (float*)alloc((size_t)NL*GDIM*sizeof(float));
  char*           ring0 = (char*)alloc((size_t)NL*RINGB);
  char*           ring1s= (char*)alloc((size_t)NL*RINGB);
  unsigned short* wihb  = (unsigned short*)alloc((size_t)NL*GDIM*HID*2);
  unsigned short* whhb  = (unsigned short*)alloc((size_t)NL*GDIM*HID*2);
  (void)ws_size;

  prep_misc<<<64, 256, 0, stream>>>(b_ih, b_hh, h0, flagz, bsum, ring0, ring1s);
  prep_w<<<1024, 256, 0, stream>>>(w_ih, w_hh, wihb, whhb);
  lstm_persist<<<256, 512, 0, stream>>>(x, c0, wihb, whhb, bsum,
                                        ring0, ring1s, flagz, out);
  (void)in_sizes; (void)n_in; (void)out_size;
}